// Round 2
// baseline (216.828 us; speedup 1.0000x reference)
//
#include <hip/hip_runtime.h>
#include <hip/hip_bf16.h>

// FC_KANLayer: B=6, T=1024, D_IN=256, D_OUT=512, NUM_GRIDS=8
// FUNC_LIST = [rbf, bs, dog, base, rbf, bs]
// All inputs/outputs f32; GEMMs run through bf16 MFMA (2%-of-max threshold).

typedef short short8 __attribute__((ext_vector_type(8)));
typedef float floatx4 __attribute__((ext_vector_type(4)));

using bf16 = __hip_bfloat16;

#define LOG2E 1.44269504088896340736f

constexpr int Tn   = 1024;
constexpr int DIN  = 256;
constexpr int DOUT = 512;
constexpr int NG   = 8;
constexpr int KSP  = DIN * NG;            // 2048
constexpr float INV_DENOM = 7.0f / 3.0f;  // 1/DENOM, DENOM = 3/7

// ---------------- LayerNorm ----------------
// grid: 6144 blocks (one per (b,t) row), 256 threads
__global__ void ln_kernel(const float* __restrict__ X,
                          const float* __restrict__ w,
                          const float* __restrict__ b,
                          float* __restrict__ Xn,
                          float* __restrict__ XnT2) {
    int row = blockIdx.x;          // b*1024 + t
    int tid = threadIdx.x;         // din
    float x = X[(size_t)row * DIN + tid];
    float s = x, ss = x * x;
    #pragma unroll
    for (int o = 32; o > 0; o >>= 1) {
        s  += __shfl_down(s, o);
        ss += __shfl_down(ss, o);
    }
    __shared__ float ps[4], pss[4], stats[2];
    int wv = tid >> 6, lane = tid & 63;
    if (lane == 0) { ps[wv] = s; pss[wv] = ss; }
    __syncthreads();
    if (tid == 0) {
        float S  = ps[0] + ps[1] + ps[2] + ps[3];
        float SS = pss[0] + pss[1] + pss[2] + pss[3];
        float mu  = S * (1.0f / DIN);
        float var = SS * (1.0f / DIN) - mu * mu;
        stats[0] = mu;
        stats[1] = rsqrtf(var + 1e-5f);
    }
    __syncthreads();
    float mu = stats[0], rstd = stats[1];
    float xn = (x - mu) * rstd * w[tid] + b[tid];
    Xn[(size_t)row * DIN + tid] = xn;
    if ((row >> 10) == 2) {
        // batch 2 also stored transposed [din][t] for the dog kernel
        XnT2[(size_t)tid * Tn + (row & 1023)] = xn;
    }
}

// ---------------- Weight f32 -> bf16 conversion ----------------
__global__ void prep_kernel(const float* __restrict__ sw,
                            const float* __restrict__ bw,
                            bf16* __restrict__ swb,
                            bf16* __restrict__ bwb) {
    int i = blockIdx.x * 256 + threadIdx.x;        // 0 .. 1048575
    swb[i] = __float2bfloat16(sw[i]);
    if (i < DOUT * DIN) bwb[i] = __float2bfloat16(bw[i]);
}

// ---------------- Basis (rbf / b-spline) + silu prep ----------------
// blocks 0..4095: spline rows (which = blk>>10 -> batches {0,1,4,5})
// blocks 4096..5119: silu rows for batch 3
__global__ void basis_kernel(const float* __restrict__ Xn,
                             const float* __restrict__ grid_rbf,
                             const float* __restrict__ grid_bs,
                             bf16* __restrict__ Amat,   // [4096][2048]
                             bf16* __restrict__ Sm) {   // [1024][256]
    int blk = blockIdx.x, tid = threadIdx.x;
    if (blk < 4096) {
        int which = blk >> 10, t = blk & 1023;
        int batch = (which == 0) ? 0 : (which == 1) ? 1 : (which == 2) ? 4 : 5;
        float x = Xn[((size_t)batch * Tn + t) * DIN + tid];
        float out[NG];
        bool is_rbf = (which == 0) || (which == 2);
        if (is_rbf) {
            #pragma unroll
            for (int j = 0; j < NG; j++) {
                float g = grid_rbf[j];
                float d = (x - g) * INV_DENOM;
                out[j] = __builtin_amdgcn_exp2f(-d * d * LOG2E);
            }
        } else {
            float g[12];
            #pragma unroll
            for (int i = 0; i < 12; i++) g[i] = grid_bs[i];
            float bs_[11];
            #pragma unroll
            for (int i = 0; i < 11; i++)
                bs_[i] = (x >= g[i] && x < g[i + 1]) ? 1.0f : 0.0f;
            #pragma unroll
            for (int k = 1; k <= 3; k++) {
                #pragma unroll
                for (int i = 0; i < 10; i++) {
                    if (i <= 10 - k) {
                        float t1 = (x - g[i]) / (g[i + k] - g[i]) * bs_[i];
                        float t2 = (g[i + k + 1] - x) / (g[i + k + 1] - g[i + 1]) * bs_[i + 1];
                        bs_[i] = t1 + t2;
                    }
                }
            }
            #pragma unroll
            for (int j = 0; j < NG; j++) out[j] = bs_[j];
        }
        short8 v;
        #pragma unroll
        for (int j = 0; j < NG; j++) {
            bf16 h = __float2bfloat16(out[j]);
            v[j] = __builtin_bit_cast(short, h);
        }
        *(short8*)((short*)Amat + (size_t)blk * KSP + (size_t)tid * NG) = v;
    } else {
        int t = blk - 4096;
        float x = Xn[((size_t)3 * Tn + t) * DIN + tid];
        float e = __builtin_amdgcn_exp2f(-x * LOG2E);
        float s = x * __builtin_amdgcn_rcpf(1.0f + e);
        Sm[(size_t)t * DIN + tid] = __float2bfloat16(s);
    }
}

// ---------------- bf16 MFMA GEMM: C[M,512] = A[M,K] * B[512,K]^T ----------------
// block = 256 threads = 4 waves; block tile 64(M) x 64(N); wave: 16 rows x 64 cols
// mode 0: spline (row -> batch {0,1,4,5}); mode 1: base (batch 3)
__global__ void gemm_kernel(const bf16* __restrict__ A,
                            const bf16* __restrict__ B,
                            float* __restrict__ out,
                            int K, int mode) {
    int tid = threadIdx.x;
    int wv = tid >> 6, lane = tid & 63;
    int m = lane & 15, q = lane >> 4;
    int row0 = blockIdx.x * 64 + wv * 16;
    int col0 = blockIdx.y * 64;

    floatx4 acc[4];
    #pragma unroll
    for (int c = 0; c < 4; c++) acc[c] = (floatx4)(0.0f);

    const short* Ar = (const short*)A + (size_t)(row0 + m) * K;
    const short* Bp = (const short*)B;

    for (int k0 = 0; k0 < K; k0 += 32) {
        short8 a = *(const short8*)(Ar + k0 + q * 8);
        #pragma unroll
        for (int c = 0; c < 4; c++) {
            short8 bf = *(const short8*)(Bp + (size_t)(col0 + c * 16 + m) * K + k0 + q * 8);
            acc[c] = __builtin_amdgcn_mfma_f32_16x16x32_bf16(a, bf, acc[c], 0, 0, 0);
        }
    }

    #pragma unroll
    for (int c = 0; c < 4; c++) {
        #pragma unroll
        for (int r = 0; r < 4; r++) {
            int row = row0 + q * 4 + r;
            int col = col0 + c * 16 + m;
            size_t off;
            if (mode == 0) {
                int which = row >> 10, t = row & 1023;
                int batch = (which == 0) ? 0 : (which == 1) ? 1 : (which == 2) ? 4 : 5;
                off = ((size_t)batch * Tn + t) * DOUT + col;
            } else {
                off = ((size_t)3 * Tn + row) * DOUT + col;
            }
            out[off] = acc[c][r];
        }
    }
}

// ---------------- DoG wavelet (batch 2) ----------------
// grid: 512 blocks (one per dout), 256 threads; each thread handles 4 t values
__global__ void dog_kernel(const float* __restrict__ XnT2,   // [256][1024]
                           const float* __restrict__ bw,     // [512][256]
                           const float* __restrict__ sc,
                           const float* __restrict__ tr,
                           float* __restrict__ out) {
    int dout = blockIdx.x, tid = threadIdx.x;
    __shared__ float rs[DIN], tt[DIN], nbw[DIN];
    {
        float s = sc[(size_t)dout * DIN + tid];
        float r = 1.0f / s;
        rs[tid]  = r;
        tt[tid]  = -tr[(size_t)dout * DIN + tid] * r;
        nbw[tid] = -bw[(size_t)dout * DIN + tid];
    }
    __syncthreads();
    float acc0 = 0.f, acc1 = 0.f, acc2 = 0.f, acc3 = 0.f;
    const float kC = -0.5f * LOG2E;
    for (int d = 0; d < DIN; d++) {
        float r = rs[d], o = tt[d], w = nbw[d];
        const float* xp = XnT2 + (size_t)d * Tn + tid;
        float x0 = xp[0], x1 = xp[256], x2 = xp[512], x3 = xp[768];
        float xs, e;
        xs = fmaf(x0, r, o); e = __builtin_amdgcn_exp2f(xs * xs * kC); acc0 = fmaf(xs * e, w, acc0);
        xs = fmaf(x1, r, o); e = __builtin_amdgcn_exp2f(xs * xs * kC); acc1 = fmaf(xs * e, w, acc1);
        xs = fmaf(x2, r, o); e = __builtin_amdgcn_exp2f(xs * xs * kC); acc2 = fmaf(xs * e, w, acc2);
        xs = fmaf(x3, r, o); e = __builtin_amdgcn_exp2f(xs * xs * kC); acc3 = fmaf(xs * e, w, acc3);
    }
    size_t base = (size_t)2 * Tn * DOUT + dout;
    out[base + (size_t)(tid +   0) * DOUT] = acc0;
    out[base + (size_t)(tid + 256) * DOUT] = acc1;
    out[base + (size_t)(tid + 512) * DOUT] = acc2;
    out[base + (size_t)(tid + 768) * DOUT] = acc3;
}

extern "C" void kernel_launch(void* const* d_in, const int* in_sizes, int n_in,
                              void* d_out, int out_size, void* d_ws, size_t ws_size,
                              hipStream_t stream) {
    const float* X        = (const float*)d_in[0];
    const float* ln_w     = (const float*)d_in[1];
    const float* ln_b     = (const float*)d_in[2];
    const float* base_w   = (const float*)d_in[3];
    const float* spline_w = (const float*)d_in[4];
    const float* scale    = (const float*)d_in[5];
    const float* transl   = (const float*)d_in[6];
    const float* grid_rbf = (const float*)d_in[7];
    const float* grid_bs  = (const float*)d_in[8];
    float* out = (float*)d_out;

    // workspace layout (25.75 MiB total)
    char* ws = (char*)d_ws;
    float* Xn   = (float*)ws;                                  // 6*1024*256 f32 = 6 MiB
    float* XnT2 = (float*)(ws + (6u << 20));                   // 256*1024 f32   = 1 MiB
    bf16*  Amat = (bf16*)(ws + (7u << 20));                    // 4096*2048 bf16 = 16 MiB
    bf16*  Sm   = (bf16*)(ws + (23u << 20));                   // 1024*256 bf16  = 0.5 MiB
    bf16*  SWb  = (bf16*)(ws + (23u << 20) + (512u << 10));    // 512*2048 bf16  = 2 MiB
    bf16*  BWb  = (bf16*)(ws + (25u << 20) + (512u << 10));    // 512*256 bf16   = 0.25 MiB

    ln_kernel<<<6 * Tn, 256, 0, stream>>>(X, ln_w, ln_b, Xn, XnT2);
    prep_kernel<<<(DOUT * KSP) / 256, 256, 0, stream>>>(spline_w, base_w, SWb, BWb);
    basis_kernel<<<4096 + 1024, 256, 0, stream>>>(Xn, grid_rbf, grid_bs, Amat, Sm);
    gemm_kernel<<<dim3(4096 / 64, DOUT / 64), 256, 0, stream>>>(Amat, SWb, out, KSP, 0);
    gemm_kernel<<<dim3(Tn / 64, DOUT / 64), 256, 0, stream>>>(Sm, BWb, out, DIN, 1);
    dog_kernel<<<DOUT, 256, 0, stream>>>(XnT2, base_w, scale, transl, out);
}

// Round 3
// 169.553 us; speedup vs baseline: 1.2788x; 1.2788x over previous
//
#include <hip/hip_runtime.h>
#include <hip/hip_bf16.h>

// FC_KANLayer: B=6, T=1024, D_IN=256, D_OUT=512, NUM_GRIDS=8
// FUNC_LIST = [rbf, bs, dog, base, rbf, bs]
// All inputs/outputs f32; GEMMs run through bf16 MFMA (2%-of-max threshold).

typedef short short8 __attribute__((ext_vector_type(8)));
typedef float floatx4 __attribute__((ext_vector_type(4)));

using bf16 = __hip_bfloat16;

#define LOG2E 1.44269504088896340736f

constexpr int Tn   = 1024;
constexpr int DIN  = 256;
constexpr int DOUT = 512;
constexpr int NG   = 8;
constexpr int KSP  = DIN * NG;            // 2048
constexpr float INV_DENOM = 7.0f / 3.0f;  // 1/DENOM, DENOM = 3/7

// ---------------- Prep: weights -> bf16, dog params transposed ----------------
// linear ranges: [0,1048576) SWb ; [1048576,1179648) BWb ;
// [1179648,1310720) rsT+ttT ; [1310720,1441792) nbwT
__global__ void prep_kernel(const float* __restrict__ sw,
                            const float* __restrict__ bw,
                            const float* __restrict__ sc,
                            const float* __restrict__ tr,
                            bf16* __restrict__ swb,
                            bf16* __restrict__ bwb,
                            float* __restrict__ rsT,
                            float* __restrict__ ttT,
                            float* __restrict__ nbwT) {
    int i = blockIdx.x * 256 + threadIdx.x;
    if (i < 1048576) {
        swb[i] = __float2bfloat16(sw[i]);
    } else if (i < 1179648) {
        int j = i - 1048576;
        bwb[j] = __float2bfloat16(bw[j]);
    } else if (i < 1310720) {
        int j = i - 1179648;
        int dout = j >> 8, din = j & 255;
        float s = sc[j];
        float r = 1.0f / s;
        rsT[din * DOUT + dout] = r;
        ttT[din * DOUT + dout] = -tr[j] * r;
    } else {
        int j = i - 1310720;
        int dout = j >> 8, din = j & 255;
        nbwT[din * DOUT + dout] = -bw[j];
    }
}

// ---------------- Fused LayerNorm + basis/silu/Xn2 ----------------
// grid: 6144 blocks (one per (b,t) row), 256 threads
__global__ void ln_basis_kernel(const float* __restrict__ X,
                                const float* __restrict__ w,
                                const float* __restrict__ b,
                                const float* __restrict__ grid_rbf,
                                const float* __restrict__ grid_bs,
                                bf16* __restrict__ Amat,   // [4096][2048]
                                bf16* __restrict__ Sm,     // [1024][256]
                                float* __restrict__ Xn2) { // [1024][256]
    int row = blockIdx.x;          // b*1024 + t
    int tid = threadIdx.x;         // din
    int batch = row >> 10, t = row & 1023;
    float x = X[(size_t)row * DIN + tid];
    float s = x, ss = x * x;
    #pragma unroll
    for (int o = 32; o > 0; o >>= 1) {
        s  += __shfl_down(s, o);
        ss += __shfl_down(ss, o);
    }
    __shared__ float ps[4], pss[4], stats[2];
    int wv = tid >> 6, lane = tid & 63;
    if (lane == 0) { ps[wv] = s; pss[wv] = ss; }
    __syncthreads();
    if (tid == 0) {
        float S  = ps[0] + ps[1] + ps[2] + ps[3];
        float SS = pss[0] + pss[1] + pss[2] + pss[3];
        float mu  = S * (1.0f / DIN);
        float var = SS * (1.0f / DIN) - mu * mu;
        stats[0] = mu;
        stats[1] = rsqrtf(var + 1e-5f);
    }
    __syncthreads();
    float xn = (x - stats[0]) * stats[1] * w[tid] + b[tid];

    if (batch == 2) {
        Xn2[(size_t)t * DIN + tid] = xn;           // coalesced row store
    } else if (batch == 3) {
        float e = __builtin_amdgcn_exp2f(-xn * LOG2E);
        float si = xn * __builtin_amdgcn_rcpf(1.0f + e);
        Sm[(size_t)t * DIN + tid] = __float2bfloat16(si);
    } else {
        int which = batch - (batch >= 4 ? 2 : 0);  // {0,1,4,5} -> {0,1,2,3}
        bool is_rbf = (batch == 0) || (batch == 4);
        float out[NG];
        if (is_rbf) {
            #pragma unroll
            for (int j = 0; j < NG; j++) {
                float g = grid_rbf[j];
                float d = (xn - g) * INV_DENOM;
                out[j] = __builtin_amdgcn_exp2f(-d * d * LOG2E);
            }
        } else {
            float g[12];
            #pragma unroll
            for (int i = 0; i < 12; i++) g[i] = grid_bs[i];
            float bs_[11];
            #pragma unroll
            for (int i = 0; i < 11; i++)
                bs_[i] = (xn >= g[i] && xn < g[i + 1]) ? 1.0f : 0.0f;
            #pragma unroll
            for (int k = 1; k <= 3; k++) {
                #pragma unroll
                for (int i = 0; i < 10; i++) {
                    if (i <= 10 - k) {
                        float t1 = (xn - g[i]) / (g[i + k] - g[i]) * bs_[i];
                        float t2 = (g[i + k + 1] - xn) / (g[i + k + 1] - g[i + 1]) * bs_[i + 1];
                        bs_[i] = t1 + t2;
                    }
                }
            }
            #pragma unroll
            for (int j = 0; j < NG; j++) out[j] = bs_[j];
        }
        short8 v;
        #pragma unroll
        for (int j = 0; j < NG; j++) {
            bf16 h = __float2bfloat16(out[j]);
            v[j] = __builtin_bit_cast(short, h);
        }
        *(short8*)((short*)Amat + (size_t)(which * Tn + t) * KSP + (size_t)tid * NG) = v;
    }
}

// ---------------- LDS-staged bf16 MFMA GEMM: C[M,512] = A[M,K] * B[512,K]^T ----
// block = 256 threads = 4 waves; tile 64(M) x 64(N), BK=32; wave = 32x32 sub-tile.
// A,B staged via global_load_lds (16B/lane); LDS row-major [64][32] -> conflict-free
// b128 fragment reads. grid (M/64, N/64); linear id % 8 keeps one M-tile per XCD.
__global__ __launch_bounds__(256) void gemm64_kernel(const bf16* __restrict__ A,
                                                     const bf16* __restrict__ B,
                                                     float* __restrict__ out,
                                                     int K, int mode) {
    __shared__ alignas(128) short ldsA[64 * 32];
    __shared__ alignas(128) short ldsB[64 * 32];
    int tid = threadIdx.x, wv = tid >> 6, lane = tid & 63;
    int m = lane & 15, q = lane >> 4;
    int wr = wv >> 1, wc = wv & 1;
    int row0 = blockIdx.x * 64, col0 = blockIdx.y * 64;

    // staging: wave wv fills rows [wv*16, wv*16+16) of each tile; lane's 16B chunk
    const short* Ag = (const short*)A + (size_t)(row0 + wv * 16 + (lane >> 2)) * K + (lane & 3) * 8;
    const short* Bg = (const short*)B + (size_t)(col0 + wv * 16 + (lane >> 2)) * K + (lane & 3) * 8;
    short* ldsA_w = ldsA + wv * 512;   // 1 KiB per wave
    short* ldsB_w = ldsB + wv * 512;

    floatx4 acc[2][2];
    #pragma unroll
    for (int r = 0; r < 2; r++)
        #pragma unroll
        for (int c = 0; c < 2; c++) acc[r][c] = (floatx4)(0.0f);

    for (int k0 = 0; k0 < K; k0 += 32) {
        __syncthreads();   // previous iter's LDS reads done
        __builtin_amdgcn_global_load_lds(
            (const __attribute__((address_space(1))) void*)(Ag + k0),
            (__attribute__((address_space(3))) void*)ldsA_w, 16, 0, 0);
        __builtin_amdgcn_global_load_lds(
            (const __attribute__((address_space(1))) void*)(Bg + k0),
            (__attribute__((address_space(3))) void*)ldsB_w, 16, 0, 0);
        __syncthreads();   // staging visible (vmcnt drained by barrier)

        short8 a0 = *(short8*)(ldsA + (wr * 32 + m) * 32 + q * 8);
        short8 a1 = *(short8*)(ldsA + (wr * 32 + 16 + m) * 32 + q * 8);
        short8 b0 = *(short8*)(ldsB + (wc * 32 + m) * 32 + q * 8);
        short8 b1 = *(short8*)(ldsB + (wc * 32 + 16 + m) * 32 + q * 8);
        acc[0][0] = __builtin_amdgcn_mfma_f32_16x16x32_bf16(a0, b0, acc[0][0], 0, 0, 0);
        acc[0][1] = __builtin_amdgcn_mfma_f32_16x16x32_bf16(a0, b1, acc[0][1], 0, 0, 0);
        acc[1][0] = __builtin_amdgcn_mfma_f32_16x16x32_bf16(a1, b0, acc[1][0], 0, 0, 0);
        acc[1][1] = __builtin_amdgcn_mfma_f32_16x16x32_bf16(a1, b1, acc[1][1], 0, 0, 0);
    }

    #pragma unroll
    for (int r = 0; r < 2; r++) {
        #pragma unroll
        for (int c = 0; c < 2; c++) {
            #pragma unroll
            for (int rr = 0; rr < 4; rr++) {
                int row = row0 + wr * 32 + r * 16 + q * 4 + rr;
                int col = col0 + wc * 32 + c * 16 + m;
                size_t off;
                if (mode == 0) {
                    int which = row >> 10, t = row & 1023;
                    int batch = (which == 0) ? 0 : (which == 1) ? 1 : (which == 2) ? 4 : 5;
                    off = ((size_t)batch * Tn + t) * DOUT + col;
                } else {
                    off = ((size_t)3 * Tn + row) * DOUT + col;
                }
                out[off] = acc[r][c][rr];
            }
        }
    }
}

// ---------------- DoG wavelet (batch 2), tiled ----------------
// grid (DOUT/64, Tn/16), 256 threads. Thread = (dout lane 0..63, t-group 0..3),
// 4 t each. X tile [16 t][256 din] in LDS (16 KiB); params read transposed
// (coalesced over dout); stores coalesced over dout.
__global__ void dog_kernel(const float* __restrict__ Xn2,    // [1024][256]
                           const float* __restrict__ rsT,    // [256][512]
                           const float* __restrict__ ttT,
                           const float* __restrict__ nbwT,
                           float* __restrict__ out) {
    __shared__ float xs_[16 * 256];
    int tid = threadIdx.x;
    int t0 = blockIdx.y * 16;
    {
        int tl = tid >> 4, seg = tid & 15;
        #pragma unroll
        for (int j = 0; j < 4; j++) {
            int c = seg + 16 * j;   // float4 chunk 0..63 of the row
            *(float4*)&xs_[tl * 256 + c * 4] =
                *(const float4*)&Xn2[(size_t)(t0 + tl) * 256 + c * 4];
        }
    }
    __syncthreads();

    int dl = tid & 63, tg = tid >> 6;
    int dout = blockIdx.x * 64 + dl;
    const float kC = -0.5f * LOG2E;
    float acc0 = 0.f, acc1 = 0.f, acc2 = 0.f, acc3 = 0.f;
    for (int d = 0; d < 256; d++) {
        float r = rsT[d * DOUT + dout];
        float o = ttT[d * DOUT + dout];
        float w = nbwT[d * DOUT + dout];
        const float* xr = xs_ + tg * 4 * 256 + d;
        float xs, e;
        xs = fmaf(xr[0],   r, o); e = __builtin_amdgcn_exp2f(xs * xs * kC); acc0 = fmaf(xs * e, w, acc0);
        xs = fmaf(xr[256], r, o); e = __builtin_amdgcn_exp2f(xs * xs * kC); acc1 = fmaf(xs * e, w, acc1);
        xs = fmaf(xr[512], r, o); e = __builtin_amdgcn_exp2f(xs * xs * kC); acc2 = fmaf(xs * e, w, acc2);
        xs = fmaf(xr[768], r, o); e = __builtin_amdgcn_exp2f(xs * xs * kC); acc3 = fmaf(xs * e, w, acc3);
    }
    size_t base = (size_t)2 * Tn * DOUT + (size_t)(t0 + tg * 4) * DOUT + dout;
    out[base + 0 * DOUT] = acc0;
    out[base + 1 * DOUT] = acc1;
    out[base + 2 * DOUT] = acc2;
    out[base + 3 * DOUT] = acc3;
}

extern "C" void kernel_launch(void* const* d_in, const int* in_sizes, int n_in,
                              void* d_out, int out_size, void* d_ws, size_t ws_size,
                              hipStream_t stream) {
    const float* X        = (const float*)d_in[0];
    const float* ln_w     = (const float*)d_in[1];
    const float* ln_b     = (const float*)d_in[2];
    const float* base_w   = (const float*)d_in[3];
    const float* spline_w = (const float*)d_in[4];
    const float* scale    = (const float*)d_in[5];
    const float* transl   = (const float*)d_in[6];
    const float* grid_rbf = (const float*)d_in[7];
    const float* grid_bs  = (const float*)d_in[8];
    float* out = (float*)d_out;

    // workspace layout (21.25 MiB)
    char* ws = (char*)d_ws;
    bf16*  Amat = (bf16*)ws;                                   // 16 MiB   [4096][2048]
    bf16*  SWb  = (bf16*)(ws + 16777216);                      // 2 MiB    [512][2048]
    bf16*  BWb  = (bf16*)(ws + 16777216 + 2097152);            // 0.25 MiB [512][256]
    bf16*  Sm   = (bf16*)(ws + 19136512);                      // 0.5 MiB  [1024][256]
    float* Xn2  = (float*)(ws + 19660800);                     // 1 MiB    [1024][256]
    float* rsT  = (float*)(ws + 20709376);                     // 0.5 MiB  [256][512]
    float* ttT  = (float*)(ws + 21233664);                     // 0.5 MiB
    float* nbwT = (float*)(ws + 21757952);                     // 0.5 MiB  (ends 22282240)

    prep_kernel<<<5632, 256, 0, stream>>>(spline_w, base_w, scale, transl,
                                          SWb, BWb, rsT, ttT, nbwT);
    ln_basis_kernel<<<6 * Tn, 256, 0, stream>>>(X, ln_w, ln_b, grid_rbf, grid_bs,
                                                Amat, Sm, Xn2);
    gemm64_kernel<<<dim3(4096 / 64, DOUT / 64), 256, 0, stream>>>(Amat, SWb, out, KSP, 0);
    gemm64_kernel<<<dim3(Tn / 64, DOUT / 64), 256, 0, stream>>>(Sm, BWb, out, DIN, 1);
    dog_kernel<<<dim3(DOUT / 64, Tn / 16), 256, 0, stream>>>(Xn2, rsT, ttT, nbwT, out);
}

// Round 4
// 158.239 us; speedup vs baseline: 1.3703x; 1.0715x over previous
//
#include <hip/hip_runtime.h>
#include <hip/hip_bf16.h>

// FC_KANLayer: B=6, T=1024, D_IN=256, D_OUT=512, NUM_GRIDS=8
// FUNC_LIST = [rbf, bs, dog, base, rbf, bs]
// All inputs/outputs f32; GEMMs via bf16 MFMA. Two launches:
//   K1 = prep(weights->bf16, dog params transposed) + LN + basis/silu
//   K2 = mega-kernel: spline GEMM + base GEMM + DoG co-scheduled (m114 overlap)

typedef short short8 __attribute__((ext_vector_type(8)));
typedef float floatx4 __attribute__((ext_vector_type(4)));

using bf16 = __hip_bfloat16;

#define LOG2E 1.44269504088896340736f

constexpr int Tn   = 1024;
constexpr int DIN  = 256;
constexpr int DOUT = 512;
constexpr int NG   = 8;
constexpr int KSP  = DIN * NG;            // 2048
constexpr float INV_DENOM = 7.0f / 3.0f;  // 1/DENOM, DENOM = 3/7

// ================= K1: LN+basis (blocks 0..6143) | prep (6144..11775) =========
__global__ void k1_kernel(const float* __restrict__ X,
                          const float* __restrict__ w,
                          const float* __restrict__ b,
                          const float* __restrict__ grid_rbf,
                          const float* __restrict__ grid_bs,
                          const float* __restrict__ sw,
                          const float* __restrict__ bw,
                          const float* __restrict__ sc,
                          const float* __restrict__ tr,
                          bf16* __restrict__ Amat,   // [4096][2048]
                          bf16* __restrict__ Sm,     // [1024][256]
                          float* __restrict__ Xn2,   // [1024][256]
                          bf16* __restrict__ swb,    // [512][2048]
                          bf16* __restrict__ bwb,    // [512][256]
                          float* __restrict__ rsT,   // [256][512]
                          float* __restrict__ ttT,
                          float* __restrict__ nbwT) {
    int tid = threadIdx.x;
    if (blockIdx.x >= 6144) {
        int i = (blockIdx.x - 6144) * 256 + tid;
        if (i < 1048576) {
            swb[i] = __float2bfloat16(sw[i]);
        } else if (i < 1179648) {
            int j = i - 1048576;
            bwb[j] = __float2bfloat16(bw[j]);
        } else if (i < 1310720) {
            int j = i - 1179648;
            int dout = j >> 8, din = j & 255;
            float r = 1.0f / sc[j];
            rsT[din * DOUT + dout] = r;
            ttT[din * DOUT + dout] = -tr[j] * r;
        } else {
            int j = i - 1310720;
            int dout = j >> 8, din = j & 255;
            nbwT[din * DOUT + dout] = -bw[j];
        }
        return;
    }
    int row = blockIdx.x;          // b*1024 + t
    int batch = row >> 10, t = row & 1023;
    float x = X[(size_t)row * DIN + tid];
    float s = x, ss = x * x;
    #pragma unroll
    for (int o = 32; o > 0; o >>= 1) {
        s  += __shfl_down(s, o);
        ss += __shfl_down(ss, o);
    }
    __shared__ float ps[4], pss[4], stats[2];
    int wv = tid >> 6, lane = tid & 63;
    if (lane == 0) { ps[wv] = s; pss[wv] = ss; }
    __syncthreads();
    if (tid == 0) {
        float S  = ps[0] + ps[1] + ps[2] + ps[3];
        float SS = pss[0] + pss[1] + pss[2] + pss[3];
        float mu  = S * (1.0f / DIN);
        float var = SS * (1.0f / DIN) - mu * mu;
        stats[0] = mu;
        stats[1] = rsqrtf(var + 1e-5f);
    }
    __syncthreads();
    float xn = (x - stats[0]) * stats[1] * w[tid] + b[tid];

    if (batch == 2) {
        Xn2[(size_t)t * DIN + tid] = xn;
    } else if (batch == 3) {
        float e = __builtin_amdgcn_exp2f(-xn * LOG2E);
        float si = xn * __builtin_amdgcn_rcpf(1.0f + e);
        Sm[(size_t)t * DIN + tid] = __float2bfloat16(si);
    } else {
        int which = batch - (batch >= 4 ? 2 : 0);  // {0,1,4,5} -> {0,1,2,3}
        bool is_rbf = (batch == 0) || (batch == 4);
        float out[NG];
        if (is_rbf) {
            #pragma unroll
            for (int j = 0; j < NG; j++) {
                float g = grid_rbf[j];
                float d = (xn - g) * INV_DENOM;
                out[j] = __builtin_amdgcn_exp2f(-d * d * LOG2E);
            }
        } else {
            float g[12];
            #pragma unroll
            for (int i = 0; i < 12; i++) g[i] = grid_bs[i];
            float bs_[11];
            #pragma unroll
            for (int i = 0; i < 11; i++)
                bs_[i] = (xn >= g[i] && xn < g[i + 1]) ? 1.0f : 0.0f;
            #pragma unroll
            for (int k = 1; k <= 3; k++) {
                #pragma unroll
                for (int i = 0; i < 10; i++) {
                    if (i <= 10 - k) {
                        float t1 = (xn - g[i]) / (g[i + k] - g[i]) * bs_[i];
                        float t2 = (g[i + k + 1] - xn) / (g[i + k + 1] - g[i + 1]) * bs_[i + 1];
                        bs_[i] = t1 + t2;
                    }
                }
            }
            #pragma unroll
            for (int j = 0; j < NG; j++) out[j] = bs_[j];
        }
        short8 v;
        #pragma unroll
        for (int j = 0; j < NG; j++) {
            bf16 h = __float2bfloat16(out[j]);
            v[j] = __builtin_bit_cast(short, h);
        }
        *(short8*)((short*)Amat + (size_t)(which * Tn + t) * KSP + (size_t)tid * NG) = v;
    }
}

// ================= K2: mega-kernel ===========================================
// blocks [0,256):  spline GEMM, 128x64 tile (mt=bid&31 -> same XCD for all nt)
// blocks [256,320): base GEMM, 128x64 tile
// blocks [320,576): DoG, 64 dout x 32 t per block
__global__ __launch_bounds__(256) void k2_kernel(const bf16* __restrict__ Amat,
                                                 const bf16* __restrict__ SWb,
                                                 const bf16* __restrict__ Sm,
                                                 const bf16* __restrict__ BWb,
                                                 const float* __restrict__ Xn2,
                                                 const float* __restrict__ rsT,
                                                 const float* __restrict__ ttT,
                                                 const float* __restrict__ nbwT,
                                                 float* __restrict__ out) {
    __shared__ alignas(16) char smem[32768];
    int bid = blockIdx.x, tid = threadIdx.x;

    if (bid < 320) {
        // ---------------- GEMM role: C[M,512] = A[M,K] * W[512,K]^T ----------
        const short* A; const short* Bw; int K, mode, row0, col0;
        if (bid < 256) {
            int mt = bid & 31, nt = bid >> 5;
            A = (const short*)Amat; Bw = (const short*)SWb;
            K = KSP; mode = 0; row0 = mt * 128; col0 = nt * 64;
        } else {
            int idx = bid - 256;
            int mt = idx & 7, nt = idx >> 3;
            A = (const short*)Sm; Bw = (const short*)BWb;
            K = DIN; mode = 1; row0 = mt * 128; col0 = nt * 64;
        }
        short* ldsA = (short*)smem;            // [128][32] = 8 KiB
        short* ldsB = (short*)(smem + 8192);   // [64][32]  = 4 KiB

        int wv = tid >> 6, lane = tid & 63;
        int m = lane & 15, q = lane >> 4;
        int wr = wv >> 1, wc = wv & 1;          // wave tile: 64(M) x 32(N)

        const short* gA0 = A  + (size_t)(row0 + wv * 16 + (lane >> 2)) * K + (lane & 3) * 8;
        const short* gA1 = gA0 + (size_t)64 * K;
        const short* gB  = Bw + (size_t)(col0 + wv * 16 + (lane >> 2)) * K + (lane & 3) * 8;
        short* ldsA0 = ldsA + wv * 512;
        short* ldsA1 = ldsA + 2048 + wv * 512;
        short* ldsB0 = ldsB + wv * 512;

        floatx4 acc[4][2];
        #pragma unroll
        for (int r = 0; r < 4; r++)
            #pragma unroll
            for (int c = 0; c < 2; c++) acc[r][c] = (floatx4)(0.0f);

        for (int k0 = 0; k0 < K; k0 += 32) {
            __syncthreads();
            __builtin_amdgcn_global_load_lds(
                (const __attribute__((address_space(1))) void*)(gA0 + k0),
                (__attribute__((address_space(3))) void*)ldsA0, 16, 0, 0);
            __builtin_amdgcn_global_load_lds(
                (const __attribute__((address_space(1))) void*)(gA1 + k0),
                (__attribute__((address_space(3))) void*)ldsA1, 16, 0, 0);
            __builtin_amdgcn_global_load_lds(
                (const __attribute__((address_space(1))) void*)(gB + k0),
                (__attribute__((address_space(3))) void*)ldsB0, 16, 0, 0);
            __syncthreads();

            short8 bfr[2];
            #pragma unroll
            for (int c = 0; c < 2; c++)
                bfr[c] = *(short8*)(ldsB + (wc * 32 + c * 16 + m) * 32 + q * 8);
            #pragma unroll
            for (int r = 0; r < 4; r++) {
                short8 a = *(short8*)(ldsA + (wr * 64 + r * 16 + m) * 32 + q * 8);
                acc[r][0] = __builtin_amdgcn_mfma_f32_16x16x32_bf16(a, bfr[0], acc[r][0], 0, 0, 0);
                acc[r][1] = __builtin_amdgcn_mfma_f32_16x16x32_bf16(a, bfr[1], acc[r][1], 0, 0, 0);
            }
        }

        #pragma unroll
        for (int r = 0; r < 4; r++) {
            #pragma unroll
            for (int c = 0; c < 2; c++) {
                #pragma unroll
                for (int rr = 0; rr < 4; rr++) {
                    int row = row0 + wr * 64 + r * 16 + q * 4 + rr;
                    int col = col0 + wc * 32 + c * 16 + m;
                    size_t off;
                    if (mode == 0) {
                        int which = row >> 10, t = row & 1023;
                        int batch = (which == 0) ? 0 : (which == 1) ? 1 : (which == 2) ? 4 : 5;
                        off = ((size_t)batch * Tn + t) * DOUT + col;
                    } else {
                        off = ((size_t)3 * Tn + row) * DOUT + col;
                    }
                    out[off] = acc[r][c][rr];
                }
            }
        }
    } else {
        // ---------------- DoG role (batch 2) --------------------------------
        int idx = bid - 320;
        int dt = idx >> 5, tt = idx & 31;
        int t0 = tt * 32;
        float* xs_ = (float*)smem;   // [32][256] = 32 KiB
        {
            int tl = tid >> 6, c = tid & 63;
            #pragma unroll
            for (int i = 0; i < 8; i++) {
                *(float4*)&xs_[(i * 4 + tl) * 256 + c * 4] =
                    *(const float4*)&Xn2[(size_t)(t0 + i * 4 + tl) * 256 + c * 4];
            }
        }
        __syncthreads();

        int dl = tid & 63, tg = tid >> 6;
        int dout = dt * 64 + dl;
        const float kC = -0.5f * LOG2E;
        float acc[8];
        #pragma unroll
        for (int j = 0; j < 8; j++) acc[j] = 0.0f;
        for (int d = 0; d < 256; d++) {
            float r = rsT[d * DOUT + dout];
            float o = ttT[d * DOUT + dout];
            float w = nbwT[d * DOUT + dout];
            const float* xr = xs_ + (tg * 8) * 256 + d;
            #pragma unroll
            for (int j = 0; j < 8; j++) {
                float xs = fmaf(xr[j * 256], r, o);
                float e = __builtin_amdgcn_exp2f(xs * xs * kC);
                acc[j] = fmaf(xs * e, w, acc[j]);
            }
        }
        size_t base = (size_t)2 * Tn * DOUT + (size_t)(t0 + tg * 8) * DOUT + dout;
        #pragma unroll
        for (int j = 0; j < 8; j++) out[base + (size_t)j * DOUT] = acc[j];
    }
}

extern "C" void kernel_launch(void* const* d_in, const int* in_sizes, int n_in,
                              void* d_out, int out_size, void* d_ws, size_t ws_size,
                              hipStream_t stream) {
    const float* X        = (const float*)d_in[0];
    const float* ln_w     = (const float*)d_in[1];
    const float* ln_b     = (const float*)d_in[2];
    const float* base_w   = (const float*)d_in[3];
    const float* spline_w = (const float*)d_in[4];
    const float* scale    = (const float*)d_in[5];
    const float* transl   = (const float*)d_in[6];
    const float* grid_rbf = (const float*)d_in[7];
    const float* grid_bs  = (const float*)d_in[8];
    float* out = (float*)d_out;

    char* ws = (char*)d_ws;
    bf16*  Amat = (bf16*)ws;                                   // 16 MiB   [4096][2048]
    bf16*  SWb  = (bf16*)(ws + 16777216);                      // 2 MiB    [512][2048]
    bf16*  BWb  = (bf16*)(ws + 16777216 + 2097152);            // 0.25 MiB [512][256]
    bf16*  Sm   = (bf16*)(ws + 19136512);                      // 0.5 MiB  [1024][256]
    float* Xn2  = (float*)(ws + 19660800);                     // 1 MiB    [1024][256]
    float* rsT  = (float*)(ws + 20709376);                     // 0.5 MiB  [256][512]
    float* ttT  = (float*)(ws + 21233664);                     // 0.5 MiB
    float* nbwT = (float*)(ws + 21757952);                     // 0.5 MiB

    k1_kernel<<<6144 + 5632, 256, 0, stream>>>(X, ln_w, ln_b, grid_rbf, grid_bs,
                                               spline_w, base_w, scale, transl,
                                               Amat, Sm, Xn2, SWb, BWb, rsT, ttT, nbwT);
    k2_kernel<<<576, 256, 0, stream>>>(Amat, SWb, Sm, BWb, Xn2, rsT, ttT, nbwT, out);
}

// Round 5
// 151.548 us; speedup vs baseline: 1.4308x; 1.0442x over previous
//
#include <hip/hip_runtime.h>
#include <hip/hip_bf16.h>

// FC_KANLayer: B=6, T=1024, D_IN=256, D_OUT=512, NUM_GRIDS=8
// FUNC_LIST = [rbf, bs, dog, base, rbf, bs]
// f32 in/out; GEMMs via bf16 MFMA.
// K1: wave-per-row LN+basis (no barriers) + prep. K2: dbuf GEMM + scalar-x dog.

typedef short short8 __attribute__((ext_vector_type(8)));
typedef float floatx4 __attribute__((ext_vector_type(4)));

using bf16 = __hip_bfloat16;

#define LOG2E 1.44269504088896340736f

constexpr int Tn   = 1024;
constexpr int DIN  = 256;
constexpr int DOUT = 512;
constexpr int NG   = 8;
constexpr int KSP  = DIN * NG;            // 2048
constexpr float INV_DENOM = 7.0f / 3.0f;  // 1/DENOM, DENOM = 3/7

// ================= K1 ========================================================
// blocks [0,1536): LN+basis, 4 rows/block (one row per wave, no barriers)
// blocks [1536,2944): prep grid-stride (weights->bf16, dog params transposed)
__global__ __launch_bounds__(256) void k1_kernel(
        const float* __restrict__ X,
        const float* __restrict__ w,
        const float* __restrict__ b,
        const float* __restrict__ grid_rbf,
        const float* __restrict__ grid_bs,
        const float* __restrict__ sw,
        const float* __restrict__ bw,
        const float* __restrict__ sc,
        const float* __restrict__ tr,
        bf16* __restrict__ Amat,   // [4096][2048]
        bf16* __restrict__ Sm,     // [1024][256]
        float* __restrict__ Xn2T,  // [256][1024]  (din-major, for dog s_loads)
        bf16* __restrict__ swb,    // [512][2048]
        bf16* __restrict__ bwb,    // [512][256]
        float* __restrict__ rsT,   // [256][512]
        float* __restrict__ ttT,
        float* __restrict__ nbwT) {
    int tid = threadIdx.x;
    if (blockIdx.x >= 1536) {
        int base = (blockIdx.x - 1536) * 1024 + tid;
        #pragma unroll
        for (int s = 0; s < 4; s++) {
            int i = base + s * 256;
            if (i < 1048576) {
                swb[i] = __float2bfloat16(sw[i]);
            } else if (i < 1179648) {
                int j = i - 1048576;
                bwb[j] = __float2bfloat16(bw[j]);
            } else if (i < 1310720) {
                int j = i - 1179648;
                int dout = j >> 8, din = j & 255;
                float r = 1.0f / sc[j];
                rsT[din * DOUT + dout] = r;
                ttT[din * DOUT + dout] = -tr[j] * r;
            } else {
                int j = i - 1310720;
                int dout = j >> 8, din = j & 255;
                nbwT[din * DOUT + dout] = -bw[j];
            }
        }
        return;
    }

    int wv = tid >> 6, lane = tid & 63;
    int row = blockIdx.x * 4 + wv;       // b*1024 + t
    int batch = row >> 10, t = row & 1023;

    float x[4];
    #pragma unroll
    for (int j = 0; j < 4; j++) x[j] = X[(size_t)row * DIN + j * 64 + lane];
    float s = x[0] + x[1] + x[2] + x[3];
    float ss = x[0] * x[0] + x[1] * x[1] + x[2] * x[2] + x[3] * x[3];
    #pragma unroll
    for (int o = 1; o < 64; o <<= 1) {
        s  += __shfl_xor(s, o);
        ss += __shfl_xor(ss, o);
    }
    float mu = s * (1.0f / DIN);
    float rstd = rsqrtf(ss * (1.0f / DIN) - mu * mu + 1e-5f);

    float xn[4];
    #pragma unroll
    for (int j = 0; j < 4; j++) {
        int din = j * 64 + lane;
        xn[j] = (x[j] - mu) * rstd * w[din] + b[din];
    }

    if (batch == 2) {
        // transposed store (scattered over din; lines merge in L2)
        #pragma unroll
        for (int j = 0; j < 4; j++)
            Xn2T[(size_t)(j * 64 + lane) * Tn + t] = xn[j];
    } else if (batch == 3) {
        #pragma unroll
        for (int j = 0; j < 4; j++) {
            float e = __builtin_amdgcn_exp2f(-xn[j] * LOG2E);
            float si = xn[j] * __builtin_amdgcn_rcpf(1.0f + e);
            Sm[(size_t)t * DIN + j * 64 + lane] = __float2bfloat16(si);
        }
    } else {
        int which = (batch == 0) ? 0 : (batch == 1) ? 1 : (batch == 4) ? 2 : 3;
        bool is_rbf = (batch == 0) || (batch == 4);
        #pragma unroll
        for (int j = 0; j < 4; j++) {
            float v = xn[j];
            float outv[NG];
            if (is_rbf) {
                #pragma unroll
                for (int g = 0; g < NG; g++) {
                    float d = (v - grid_rbf[g]) * INV_DENOM;
                    outv[g] = __builtin_amdgcn_exp2f(-d * d * LOG2E);
                }
            } else {
                float g[12];
                #pragma unroll
                for (int i = 0; i < 12; i++) g[i] = grid_bs[i];
                float ih = 1.0f / (g[1] - g[0]);           // uniform spacing
                float ihk[3] = {ih, ih * 0.5f, ih * (1.0f / 3.0f)};
                float bs_[11];
                #pragma unroll
                for (int i = 0; i < 11; i++)
                    bs_[i] = (v >= g[i] && v < g[i + 1]) ? 1.0f : 0.0f;
                #pragma unroll
                for (int k = 1; k <= 3; k++) {
                    float rk = ihk[k - 1];
                    #pragma unroll
                    for (int i = 0; i < 10; i++) {
                        if (i <= 10 - k) {
                            bs_[i] = (v - g[i]) * rk * bs_[i]
                                   + (g[i + k + 1] - v) * rk * bs_[i + 1];
                        }
                    }
                }
                #pragma unroll
                for (int gg = 0; gg < NG; gg++) outv[gg] = bs_[gg];
            }
            short8 pv;
            #pragma unroll
            for (int gg = 0; gg < NG; gg++) {
                bf16 h = __float2bfloat16(outv[gg]);
                pv[gg] = __builtin_bit_cast(short, h);
            }
            // row (which*1024+t), cols din*8..din*8+8 ; inst j: 64 lanes x 16B contig
            *(short8*)((short*)Amat + (size_t)(which * Tn + t) * KSP
                       + (size_t)(j * 64 + lane) * NG) = pv;
        }
    }
}

// ================= K2: mega-kernel ===========================================
// bids [0,256):  spline GEMM 128x64, mt=bid&31 (XCD=mt%8 -> A slice L2-resident)
// bids [256,320): base GEMM 128x64, K=256
// bids [320,576): DoG, 64 dout x 32 t, x via scalar loads, no LDS/barriers
__global__ __launch_bounds__(256) void k2_kernel(const bf16* __restrict__ Amat,
                                                 const bf16* __restrict__ SWb,
                                                 const bf16* __restrict__ Sm,
                                                 const bf16* __restrict__ BWb,
                                                 const float* __restrict__ Xn2T,
                                                 const float* __restrict__ rsT,
                                                 const float* __restrict__ ttT,
                                                 const float* __restrict__ nbwT,
                                                 float* __restrict__ out) {
    __shared__ alignas(16) char smem[24576];
    int bid = blockIdx.x, tid = threadIdx.x;

    if (bid < 320) {
        // -------- GEMM role: C[M,512] = A[M,K] * W[512,K]^T, dbuf ping-pong --
        const short* A; const short* Bw; int K, mode, row0, col0;
        if (bid < 256) {
            int mt = bid & 31, nt = bid >> 5;
            A = (const short*)Amat; Bw = (const short*)SWb;
            K = KSP; mode = 0; row0 = mt * 128; col0 = nt * 64;
        } else {
            int idx = bid - 256;
            int mt = idx & 7, nt = idx >> 3;
            A = (const short*)Sm; Bw = (const short*)BWb;
            K = DIN; mode = 1; row0 = mt * 128; col0 = nt * 64;
        }
        short* ldsA = (short*)smem;            // [2][128][32] = 16 KiB
        short* ldsB = (short*)(smem + 16384);  // [2][64][32]  =  8 KiB

        int wv = tid >> 6, lane = tid & 63;
        int m = lane & 15, q = lane >> 4;
        int wr = wv >> 1, wc = wv & 1;          // wave tile: 64(M) x 32(N)

        const short* gA0 = A  + (size_t)(row0 + wv * 16 + (lane >> 2)) * K + (lane & 3) * 8;
        const short* gA1 = gA0 + (size_t)64 * K;
        const short* gB  = Bw + (size_t)(col0 + wv * 16 + (lane >> 2)) * K + (lane & 3) * 8;

        floatx4 acc[4][2];
        #pragma unroll
        for (int r = 0; r < 4; r++)
            #pragma unroll
            for (int c = 0; c < 2; c++) acc[r][c] = (floatx4)(0.0f);

        int iters = K >> 5;
        // prologue: stage tile 0 into buffer 0
        {
            short* dA = ldsA + wv * 512;
            __builtin_amdgcn_global_load_lds(
                (const __attribute__((address_space(1))) void*)gA0,
                (__attribute__((address_space(3))) void*)dA, 16, 0, 0);
            __builtin_amdgcn_global_load_lds(
                (const __attribute__((address_space(1))) void*)gA1,
                (__attribute__((address_space(3))) void*)(dA + 2048), 16, 0, 0);
            __builtin_amdgcn_global_load_lds(
                (const __attribute__((address_space(1))) void*)gB,
                (__attribute__((address_space(3))) void*)(ldsB + wv * 512), 16, 0, 0);
        }
        for (int i = 0; i < iters; i++) {
            int cur = i & 1;
            __syncthreads();   // drains own vmcnt -> tile i visible everywhere
            if (i + 1 < iters) {
                int nxt = cur ^ 1, k0 = (i + 1) * 32;
                short* dA = ldsA + nxt * 4096 + wv * 512;
                __builtin_amdgcn_global_load_lds(
                    (const __attribute__((address_space(1))) void*)(gA0 + k0),
                    (__attribute__((address_space(3))) void*)dA, 16, 0, 0);
                __builtin_amdgcn_global_load_lds(
                    (const __attribute__((address_space(1))) void*)(gA1 + k0),
                    (__attribute__((address_space(3))) void*)(dA + 2048), 16, 0, 0);
                __builtin_amdgcn_global_load_lds(
                    (const __attribute__((address_space(1))) void*)(gB + k0),
                    (__attribute__((address_space(3))) void*)(ldsB + nxt * 2048 + wv * 512),
                    16, 0, 0);
            }
            const short* bA = ldsA + cur * 4096;
            const short* bB = ldsB + cur * 2048;
            short8 bfr[2];
            #pragma unroll
            for (int c = 0; c < 2; c++)
                bfr[c] = *(const short8*)(bB + (wc * 32 + c * 16 + m) * 32 + q * 8);
            #pragma unroll
            for (int r = 0; r < 4; r++) {
                short8 a = *(const short8*)(bA + (wr * 64 + r * 16 + m) * 32 + q * 8);
                acc[r][0] = __builtin_amdgcn_mfma_f32_16x16x32_bf16(a, bfr[0], acc[r][0], 0, 0, 0);
                acc[r][1] = __builtin_amdgcn_mfma_f32_16x16x32_bf16(a, bfr[1], acc[r][1], 0, 0, 0);
            }
        }

        #pragma unroll
        for (int r = 0; r < 4; r++) {
            #pragma unroll
            for (int c = 0; c < 2; c++) {
                #pragma unroll
                for (int rr = 0; rr < 4; rr++) {
                    int row = row0 + wr * 64 + r * 16 + q * 4 + rr;
                    int col = col0 + wc * 32 + c * 16 + m;
                    size_t off;
                    if (mode == 0) {
                        int which = row >> 10, t = row & 1023;
                        int batch = (which == 0) ? 0 : (which == 1) ? 1 : (which == 2) ? 4 : 5;
                        off = ((size_t)batch * Tn + t) * DOUT + col;
                    } else {
                        off = ((size_t)3 * Tn + row) * DOUT + col;
                    }
                    out[off] = acc[r][c][rr];
                }
            }
        }
    } else {
        // -------- DoG role (batch 2): no LDS, x via scalar loads -------------
        int idx = bid - 320;                 // 0..255
        int dt = idx & 7, tt = idx >> 3;     // dt%8 -> XCD locality on params
        int dl = tid & 63;
        int tg = __builtin_amdgcn_readfirstlane(tid >> 6);  // wave-uniform
        int dout = dt * 64 + dl;
        int t_base = tt * 32 + tg * 8;

        const float kC = -0.5f * LOG2E;
        float acc[8];
        #pragma unroll
        for (int j = 0; j < 8; j++) acc[j] = 0.0f;

        for (int d = 0; d < DIN; d++) {
            const float* xw = Xn2T + (size_t)d * Tn + t_base;   // uniform -> s_load
            float r = rsT[d * DOUT + dout];
            float o = ttT[d * DOUT + dout];
            float w = nbwT[d * DOUT + dout];
            #pragma unroll
            for (int j = 0; j < 8; j++) {
                float xs = fmaf(xw[j], r, o);
                float e = __builtin_amdgcn_exp2f(xs * xs * kC);
                acc[j] = fmaf(xs * e, w, acc[j]);
            }
        }
        size_t base = (size_t)2 * Tn * DOUT + (size_t)t_base * DOUT + dout;
        #pragma unroll
        for (int j = 0; j < 8; j++) out[base + (size_t)j * DOUT] = acc[j];
    }
}

extern "C" void kernel_launch(void* const* d_in, const int* in_sizes, int n_in,
                              void* d_out, int out_size, void* d_ws, size_t ws_size,
                              hipStream_t stream) {
    const float* X        = (const float*)d_in[0];
    const float* ln_w     = (const float*)d_in[1];
    const float* ln_b     = (const float*)d_in[2];
    const float* base_w   = (const float*)d_in[3];
    const float* spline_w = (const float*)d_in[4];
    const float* scale    = (const float*)d_in[5];
    const float* transl   = (const float*)d_in[6];
    const float* grid_rbf = (const float*)d_in[7];
    const float* grid_bs  = (const float*)d_in[8];
    float* out = (float*)d_out;

    char* ws = (char*)d_ws;
    bf16*  Amat = (bf16*)ws;                                   // 16 MiB   [4096][2048]
    bf16*  SWb  = (bf16*)(ws + 16777216);                      // 2 MiB    [512][2048]
    bf16*  BWb  = (bf16*)(ws + 16777216 + 2097152);            // 0.25 MiB [512][256]
    bf16*  Sm   = (bf16*)(ws + 19136512);                      // 0.5 MiB  [1024][256]
    float* Xn2T = (float*)(ws + 19660800);                     // 1 MiB    [256][1024]
    float* rsT  = (float*)(ws + 20709376);                     // 0.5 MiB  [256][512]
    float* ttT  = (float*)(ws + 21233664);                     // 0.5 MiB
    float* nbwT = (float*)(ws + 21757952);                     // 0.5 MiB

    k1_kernel<<<2944, 256, 0, stream>>>(X, ln_w, ln_b, grid_rbf, grid_bs,
                                        spline_w, base_w, scale, transl,
                                        Amat, Sm, Xn2T, SWb, BWb, rsT, ttT, nbwT);
    k2_kernel<<<576, 256, 0, stream>>>(Amat, SWb, Sm, BWb, Xn2T, rsT, ttT, nbwT, out);
}

// Round 6
// 150.515 us; speedup vs baseline: 1.4406x; 1.0069x over previous
//
#include <hip/hip_runtime.h>
#include <hip/hip_bf16.h>

// FC_KANLayer: B=6, T=1024, D_IN=256, D_OUT=512, NUM_GRIDS=8
// FUNC_LIST = [rbf, bs, dog, base, rbf, bs]
// f32 in/out; GEMMs via bf16 MFMA.
// K1: wave-per-row LN+basis (no barriers) + prep.
// K2: mega-kernel — GEMM with DIRECT global fragment loads (no LDS, no barriers,
//     register ping-pong prefetch) + dog with LDS x-tile (R3-proven form).

typedef short short8 __attribute__((ext_vector_type(8)));
typedef float floatx4 __attribute__((ext_vector_type(4)));

using bf16 = __hip_bfloat16;

#define LOG2E 1.44269504088896340736f

constexpr int Tn   = 1024;
constexpr int DIN  = 256;
constexpr int DOUT = 512;
constexpr int NG   = 8;
constexpr int KSP  = DIN * NG;            // 2048
constexpr float INV_DENOM = 7.0f / 3.0f;  // 1/DENOM, DENOM = 3/7

// ================= K1 ========================================================
// blocks [0,1536): LN+basis, 4 rows/block (one row per wave, no barriers)
// blocks [1536,2944): prep grid-stride (weights->bf16, dog params transposed)
__global__ __launch_bounds__(256) void k1_kernel(
        const float* __restrict__ X,
        const float* __restrict__ w,
        const float* __restrict__ b,
        const float* __restrict__ grid_rbf,
        const float* __restrict__ grid_bs,
        const float* __restrict__ sw,
        const float* __restrict__ bw,
        const float* __restrict__ sc,
        const float* __restrict__ tr,
        bf16* __restrict__ Amat,   // [4096][2048]
        bf16* __restrict__ Sm,     // [1024][256]
        float* __restrict__ Xn2,   // [1024][256] row-major
        bf16* __restrict__ swb,    // [512][2048]
        bf16* __restrict__ bwb,    // [512][256]
        float* __restrict__ rsT,   // [256][512]
        float* __restrict__ ttT,
        float* __restrict__ nbwT) {
    int tid = threadIdx.x;
    if (blockIdx.x >= 1536) {
        int base = (blockIdx.x - 1536) * 1024 + tid;
        #pragma unroll
        for (int s = 0; s < 4; s++) {
            int i = base + s * 256;
            if (i < 1048576) {
                swb[i] = __float2bfloat16(sw[i]);
            } else if (i < 1179648) {
                int j = i - 1048576;
                bwb[j] = __float2bfloat16(bw[j]);
            } else if (i < 1310720) {
                int j = i - 1179648;
                int dout = j >> 8, din = j & 255;
                float r = 1.0f / sc[j];
                rsT[din * DOUT + dout] = r;
                ttT[din * DOUT + dout] = -tr[j] * r;
            } else {
                int j = i - 1310720;
                int dout = j >> 8, din = j & 255;
                nbwT[din * DOUT + dout] = -bw[j];
            }
        }
        return;
    }

    int wv = tid >> 6, lane = tid & 63;
    int row = blockIdx.x * 4 + wv;       // b*1024 + t
    int batch = row >> 10, t = row & 1023;

    float x[4];
    #pragma unroll
    for (int j = 0; j < 4; j++) x[j] = X[(size_t)row * DIN + j * 64 + lane];
    float s = x[0] + x[1] + x[2] + x[3];
    float ss = x[0] * x[0] + x[1] * x[1] + x[2] * x[2] + x[3] * x[3];
    #pragma unroll
    for (int o = 1; o < 64; o <<= 1) {
        s  += __shfl_xor(s, o);
        ss += __shfl_xor(ss, o);
    }
    float mu = s * (1.0f / DIN);
    float rstd = rsqrtf(ss * (1.0f / DIN) - mu * mu + 1e-5f);

    float xn[4];
    #pragma unroll
    for (int j = 0; j < 4; j++) {
        int din = j * 64 + lane;
        xn[j] = (x[j] - mu) * rstd * w[din] + b[din];
    }

    if (batch == 2) {
        #pragma unroll
        for (int j = 0; j < 4; j++)
            Xn2[(size_t)t * DIN + j * 64 + lane] = xn[j];
    } else if (batch == 3) {
        #pragma unroll
        for (int j = 0; j < 4; j++) {
            float e = __builtin_amdgcn_exp2f(-xn[j] * LOG2E);
            float si = xn[j] * __builtin_amdgcn_rcpf(1.0f + e);
            Sm[(size_t)t * DIN + j * 64 + lane] = __float2bfloat16(si);
        }
    } else {
        int which = (batch == 0) ? 0 : (batch == 1) ? 1 : (batch == 4) ? 2 : 3;
        bool is_rbf = (batch == 0) || (batch == 4);
        #pragma unroll
        for (int j = 0; j < 4; j++) {
            float v = xn[j];
            float outv[NG];
            if (is_rbf) {
                #pragma unroll
                for (int g = 0; g < NG; g++) {
                    float d = (v - grid_rbf[g]) * INV_DENOM;
                    outv[g] = __builtin_amdgcn_exp2f(-d * d * LOG2E);
                }
            } else {
                float g[12];
                #pragma unroll
                for (int i = 0; i < 12; i++) g[i] = grid_bs[i];
                float ih = 1.0f / (g[1] - g[0]);           // uniform spacing
                float ihk[3] = {ih, ih * 0.5f, ih * (1.0f / 3.0f)};
                float bs_[11];
                #pragma unroll
                for (int i = 0; i < 11; i++)
                    bs_[i] = (v >= g[i] && v < g[i + 1]) ? 1.0f : 0.0f;
                #pragma unroll
                for (int k = 1; k <= 3; k++) {
                    float rk = ihk[k - 1];
                    #pragma unroll
                    for (int i = 0; i < 10; i++) {
                        if (i <= 10 - k) {
                            bs_[i] = (v - g[i]) * rk * bs_[i]
                                   + (g[i + k + 1] - v) * rk * bs_[i + 1];
                        }
                    }
                }
                #pragma unroll
                for (int gg = 0; gg < NG; gg++) outv[gg] = bs_[gg];
            }
            short8 pv;
            #pragma unroll
            for (int gg = 0; gg < NG; gg++) {
                bf16 h = __float2bfloat16(outv[gg]);
                pv[gg] = __builtin_bit_cast(short, h);
            }
            *(short8*)((short*)Amat + (size_t)(which * Tn + t) * KSP
                       + (size_t)(j * 64 + lane) * NG) = pv;
        }
    }
}

// -------- GEMM role: direct global fragment loads, register ping-pong --------
// C[M,512] = A[M,K] * W[512,K]^T ; wave tile 64(M) x 32(N) (4x2 MFMA frags)
template <int K, int MODE>
__device__ __forceinline__ void gemm_role(const short* __restrict__ A,
                                          const short* __restrict__ Bw,
                                          float* __restrict__ out,
                                          int row0, int col0, int tid) {
    int wv = tid >> 6, lane = tid & 63;
    int m = lane & 15, q = lane >> 4;
    int wr = wv >> 1, wc = wv & 1;

    const short8* ar[4];
    const short8* br[2];
    #pragma unroll
    for (int r = 0; r < 4; r++)
        ar[r] = (const short8*)(A + (size_t)(row0 + wr * 64 + r * 16 + m) * K + q * 8);
    #pragma unroll
    for (int c = 0; c < 2; c++)
        br[c] = (const short8*)(Bw + (size_t)(col0 + wc * 32 + c * 16 + m) * K + q * 8);
    // k advances in units of 4 short8 (32 shorts)

    floatx4 acc[4][2];
    #pragma unroll
    for (int r = 0; r < 4; r++)
        #pragma unroll
        for (int c = 0; c < 2; c++) acc[r][c] = (floatx4)(0.0f);

    short8 af[2][4], bfv[2][2];
    #pragma unroll
    for (int r = 0; r < 4; r++) af[0][r] = ar[r][0];
    #pragma unroll
    for (int c = 0; c < 2; c++) bfv[0][c] = br[c][0];

    for (int k0 = 0; k0 < K; k0 += 64) {
        int s1 = (k0 + 32) >> 3;   // short8 index of k0+32
        #pragma unroll
        for (int r = 0; r < 4; r++) af[1][r] = ar[r][s1];
        #pragma unroll
        for (int c = 0; c < 2; c++) bfv[1][c] = br[c][s1];
        #pragma unroll
        for (int r = 0; r < 4; r++) {
            acc[r][0] = __builtin_amdgcn_mfma_f32_16x16x32_bf16(af[0][r], bfv[0][0], acc[r][0], 0, 0, 0);
            acc[r][1] = __builtin_amdgcn_mfma_f32_16x16x32_bf16(af[0][r], bfv[0][1], acc[r][1], 0, 0, 0);
        }
        if (k0 + 64 < K) {
            int s2 = (k0 + 64) >> 3;
            #pragma unroll
            for (int r = 0; r < 4; r++) af[0][r] = ar[r][s2];
            #pragma unroll
            for (int c = 0; c < 2; c++) bfv[0][c] = br[c][s2];
        }
        #pragma unroll
        for (int r = 0; r < 4; r++) {
            acc[r][0] = __builtin_amdgcn_mfma_f32_16x16x32_bf16(af[1][r], bfv[1][0], acc[r][0], 0, 0, 0);
            acc[r][1] = __builtin_amdgcn_mfma_f32_16x16x32_bf16(af[1][r], bfv[1][1], acc[r][1], 0, 0, 0);
        }
    }

    #pragma unroll
    for (int r = 0; r < 4; r++) {
        #pragma unroll
        for (int c = 0; c < 2; c++) {
            #pragma unroll
            for (int rr = 0; rr < 4; rr++) {
                int row = row0 + wr * 64 + r * 16 + q * 4 + rr;
                int col = col0 + wc * 32 + c * 16 + m;
                size_t off;
                if (MODE == 0) {
                    int which = row >> 10, t = row & 1023;
                    int batch = (which == 0) ? 0 : (which == 1) ? 1 : (which == 2) ? 4 : 5;
                    off = ((size_t)batch * Tn + t) * DOUT + col;
                } else {
                    off = ((size_t)3 * Tn + row) * DOUT + col;
                }
                out[off] = acc[r][c][rr];
            }
        }
    }
}

// ================= K2: mega-kernel ===========================================
// bids [0,256):  spline GEMM 128x64 (mt=bid&31 -> XCD=bid%8 holds A slice + B)
// bids [256,320): base GEMM 128x64, K=256
// bids [320,576): DoG, 64 dout x 32 t, x-tile in LDS (broadcast reads)
__global__ __launch_bounds__(256, 2) void k2_kernel(const bf16* __restrict__ Amat,
                                                    const bf16* __restrict__ SWb,
                                                    const bf16* __restrict__ Sm,
                                                    const bf16* __restrict__ BWb,
                                                    const float* __restrict__ Xn2,
                                                    const float* __restrict__ rsT,
                                                    const float* __restrict__ ttT,
                                                    const float* __restrict__ nbwT,
                                                    float* __restrict__ out) {
    __shared__ float xs_[32 * 256];   // dog only (32 KiB)
    int bid = blockIdx.x, tid = threadIdx.x;

    if (bid < 256) {
        int mt = bid & 31, nt = bid >> 5;
        gemm_role<KSP, 0>((const short*)Amat, (const short*)SWb, out,
                          mt * 128, nt * 64, tid);
    } else if (bid < 320) {
        int idx = bid - 256;
        int mt = idx & 7, nt = idx >> 3;
        gemm_role<DIN, 1>((const short*)Sm, (const short*)BWb, out,
                          mt * 128, nt * 64, tid);
    } else {
        // -------- DoG role (batch 2) -----------------------------------------
        int idx = bid - 320;                 // 0..255
        int dt = idx & 7, tt = idx >> 3;
        int t0 = tt * 32;
        {
            int tl = tid >> 6, c = tid & 63;
            #pragma unroll
            for (int i = 0; i < 8; i++) {
                *(float4*)&xs_[(i * 4 + tl) * 256 + c * 4] =
                    *(const float4*)&Xn2[(size_t)(t0 + i * 4 + tl) * 256 + c * 4];
            }
        }
        __syncthreads();

        int dl = tid & 63, tg = tid >> 6;
        int dout = dt * 64 + dl;
        const float kC = -0.5f * LOG2E;
        float acc[8];
        #pragma unroll
        for (int j = 0; j < 8; j++) acc[j] = 0.0f;
        #pragma unroll 4
        for (int d = 0; d < DIN; d++) {
            float r = rsT[d * DOUT + dout];
            float o = ttT[d * DOUT + dout];
            float w = nbwT[d * DOUT + dout];
            const float* xr = xs_ + (tg * 8) * 256 + d;
            #pragma unroll
            for (int j = 0; j < 8; j++) {
                float xs = fmaf(xr[j * 256], r, o);
                float e = __builtin_amdgcn_exp2f(xs * xs * kC);
                acc[j] = fmaf(xs * e, w, acc[j]);
            }
        }
        size_t base = (size_t)2 * Tn * DOUT + (size_t)(t0 + tg * 8) * DOUT + dout;
        #pragma unroll
        for (int j = 0; j < 8; j++) out[base + (size_t)j * DOUT] = acc[j];
    }
}

extern "C" void kernel_launch(void* const* d_in, const int* in_sizes, int n_in,
                              void* d_out, int out_size, void* d_ws, size_t ws_size,
                              hipStream_t stream) {
    const float* X        = (const float*)d_in[0];
    const float* ln_w     = (const float*)d_in[1];
    const float* ln_b     = (const float*)d_in[2];
    const float* base_w   = (const float*)d_in[3];
    const float* spline_w = (const float*)d_in[4];
    const float* scale    = (const float*)d_in[5];
    const float* transl   = (const float*)d_in[6];
    const float* grid_rbf = (const float*)d_in[7];
    const float* grid_bs  = (const float*)d_in[8];
    float* out = (float*)d_out;

    char* ws = (char*)d_ws;
    bf16*  Amat = (bf16*)ws;                                   // 16 MiB   [4096][2048]
    bf16*  SWb  = (bf16*)(ws + 16777216);                      // 2 MiB    [512][2048]
    bf16*  BWb  = (bf16*)(ws + 16777216 + 2097152);            // 0.25 MiB [512][256]
    bf16*  Sm   = (bf16*)(ws + 19136512);                      // 0.5 MiB  [1024][256]
    float* Xn2  = (float*)(ws + 19660800);                     // 1 MiB    [1024][256]
    float* rsT  = (float*)(ws + 20709376);                     // 0.5 MiB  [256][512]
    float* ttT  = (float*)(ws + 21233664);                     // 0.5 MiB
    float* nbwT = (float*)(ws + 21757952);                     // 0.5 MiB

    k1_kernel<<<2944, 256, 0, stream>>>(X, ln_w, ln_b, grid_rbf, grid_bs,
                                        spline_w, base_w, scale, transl,
                                        Amat, Sm, Xn2, SWb, BWb, rsT, ttT, nbwT);
    k2_kernel<<<576, 256, 0, stream>>>(Amat, SWb, Sm, BWb, Xn2, rsT, ttT, nbwT, out);
}